// Round 3
// baseline (33.892 us; speedup 1.0000x reference)
//
#include <hip/hip_runtime.h>

#define BUF     50
#define MAXK    10
#define NPAD    49        // BUF-1
#define BLK     256
#define HIDDEN  512
#define H4      128       // HIDDEN/4 float4 per row
#define SEQ     4096
#define PPB     32        // positions per block

typedef float v4f __attribute__((ext_vector_type(4)));  // native vector: OK for nontemporal builtins

// ---------------------------------------------------------------------------
// Fused kernel. Block = 256 threads, owns PPB=32 consecutive positions.
// Phase 1: stage close[base-49 .. base+31] (81 floats) in LDS; lanes 0..31 of
//          wave 0 compute Higuchi FD (fully unrolled) into LDS.
// Phase 2: all 4 waves stream 32 rows x 512 floats of output as coalesced
//          nontemporal v4f stores; each thread's column block (tid&127) is
//          loop-invariant so W/b sit in registers.
// ---------------------------------------------------------------------------
__global__ __launch_bounds__(BLK) void fused_kernel(
    const float* __restrict__ x, const v4f* __restrict__ W4,
    const v4f* __restrict__ b4, v4f* __restrict__ out, int P) {
    __shared__ float sm_close[PPB + NPAD];  // 81
    __shared__ float sm_fd[PPB];

    const int base = blockIdx.x * PPB;
    const int tid = threadIdx.x;

    if (tid < PPB + NPAD) {
        const int src = base - NPAD + tid;
        sm_close[tid] = (src >= 0) ? x[src * 8 + 3] : 0.0f;  // close = x[:,:,3]
    }
    __syncthreads();

    if (tid < PPB) {
        float w[BUF];
#pragma unroll
        for (int j = 0; j < BUF; ++j) w[j] = sm_close[tid + j];

        const float logk_tab[MAXK] = {0.0f,        0.69314718f, 1.09861229f,
                                      1.38629436f, 1.60943791f, 1.79175947f,
                                      1.94591015f, 2.07944154f, 2.19722458f,
                                      2.30258509f};

        float Sw = 0.0f, Sx = 0.0f, Sy = 0.0f, Sxx = 0.0f, Sxy = 0.0f;
#pragma unroll
        for (int k = 1; k <= MAXK; ++k) {
            float acc = 0.0f;
#pragma unroll
            for (int m = 0; m < k; ++m) {
                const int Nm = (NPAD - m) / k + 1;  // len(arange(m, BUF, k))
                if (Nm >= 2) {
                    float len = 0.0f;
#pragma unroll
                    for (int i = 1; i < Nm; ++i)
                        len += fabsf(w[m + i * k] - w[m + (i - 1) * k]);
                    acc += len * ((float)NPAD / ((float)Nm * (float)k));
                }
            }
            const float lk = acc / (float)k;
            if (lk > 0.0f) {
                const float lg = logk_tab[k - 1];
                const float ly = logf(fmaxf(lk, 1e-30f));
                Sw += 1.0f;
                Sx += lg;
                Sy += ly;
                Sxx += lg * lg;
                Sxy += lg * ly;
            }
        }
        const float denom = Sw * Sxx - Sx * Sx;
        const float slope =
            (fabsf(denom) > 1e-12f) ? (Sw * Sxy - Sx * Sy) / denom : 0.0f;
        float fd = (Sw > 1.0f) ? -slope : 0.0f;

        const int s = (base + tid) & (SEQ - 1);  // time mask: s < MAX_K -> 0
        if (s < MAXK) fd = 0.0f;
        sm_fd[tid] = fd;
    }
    __syncthreads();

    // Phase 2: 32 rows * 128 v4f = 4096 v4f per block, 16 per thread.
    const int h4 = tid & (H4 - 1);          // loop-invariant column block
    const int rbase = tid >> 7;             // 0 or 1
    const v4f Wv = W4[h4];
    const v4f bv = b4[h4];
    v4f* outb = out + (size_t)base * H4 + h4;
#pragma unroll
    for (int i = 0; i < PPB / 2; ++i) {
        const int row = i * 2 + rbase;
        const float h = sm_fd[row];
        v4f o;
        o.x = fmaxf(fmaf(h, Wv.x, bv.x), 0.0f);
        o.y = fmaxf(fmaf(h, Wv.y, bv.y), 0.0f);
        o.z = fmaxf(fmaf(h, Wv.z, bv.z), 0.0f);
        o.w = fmaxf(fmaf(h, Wv.w, bv.w), 0.0f);
        __builtin_nontemporal_store(o, outb + (size_t)row * H4);
    }
}

extern "C" void kernel_launch(void* const* d_in, const int* in_sizes, int n_in,
                              void* d_out, int out_size, void* d_ws,
                              size_t ws_size, hipStream_t stream) {
    const float* x = (const float*)d_in[0];   // (16, 4096, 8)
    const v4f* W4 = (const v4f*)d_in[1];      // (512,1) contiguous
    const v4f* b4 = (const v4f*)d_in[2];      // (512,)
    v4f* out = (v4f*)d_out;                   // (16, 4096, 512) fp32

    const int P = in_sizes[0] / 8;            // 65536 positions
    fused_kernel<<<P / PPB, BLK, 0, stream>>>(x, W4, b4, out, P);
}

// Round 4
// 29.578 us; speedup vs baseline: 1.1459x; 1.1459x over previous
//
#include <hip/hip_runtime.h>

#define BUF     50
#define MAXK    10
#define NPAD    49        // BUF-1
#define BLK     256
#define HIDDEN  512
#define H4      128       // HIDDEN/4 float4 per row
#define SEQ     4096
#define PPB     32        // positions per block

typedef float v4f __attribute__((ext_vector_type(4)));

// ---------------------------------------------------------------------------
// Fused kernel. Block = 256 threads, owns PPB=32 consecutive positions.
// Phase 1: stage close[base-49 .. base+31] (81 floats) in LDS; lanes 0..31 of
//          wave 0 compute Higuchi FD (fully unrolled) into LDS.
// Phase 2: hoist the 32 fd values to registers (wave-broadcast LDS reads),
//          then all 4 waves stream 32 rows x 512 floats as coalesced PLAIN
//          float4 stores (nt flag removed — fills prove plain stores reach
//          86% of peak; suspect nt demoted write efficiency in round 3).
// ---------------------------------------------------------------------------
__global__ __launch_bounds__(BLK) void fused_kernel(
    const float* __restrict__ x, const v4f* __restrict__ W4,
    const v4f* __restrict__ b4, v4f* __restrict__ out, int P) {
    __shared__ float sm_close[PPB + NPAD];  // 81
    __shared__ float sm_fd[PPB];

    const int base = blockIdx.x * PPB;
    const int tid = threadIdx.x;

    if (tid < PPB + NPAD) {
        const int src = base - NPAD + tid;
        sm_close[tid] = (src >= 0) ? x[src * 8 + 3] : 0.0f;  // close = x[:,:,3]
    }
    __syncthreads();

    if (tid < PPB) {
        float w[BUF];
#pragma unroll
        for (int j = 0; j < BUF; ++j) w[j] = sm_close[tid + j];

        const float logk_tab[MAXK] = {0.0f,        0.69314718f, 1.09861229f,
                                      1.38629436f, 1.60943791f, 1.79175947f,
                                      1.94591015f, 2.07944154f, 2.19722458f,
                                      2.30258509f};

        float Sw = 0.0f, Sx = 0.0f, Sy = 0.0f, Sxx = 0.0f, Sxy = 0.0f;
#pragma unroll
        for (int k = 1; k <= MAXK; ++k) {
            float acc = 0.0f;
#pragma unroll
            for (int m = 0; m < k; ++m) {
                const int Nm = (NPAD - m) / k + 1;  // len(arange(m, BUF, k))
                if (Nm >= 2) {
                    float len = 0.0f;
#pragma unroll
                    for (int i = 1; i < Nm; ++i)
                        len += fabsf(w[m + i * k] - w[m + (i - 1) * k]);
                    acc += len * ((float)NPAD / ((float)Nm * (float)k));
                }
            }
            const float lk = acc / (float)k;
            if (lk > 0.0f) {
                const float lg = logk_tab[k - 1];
                const float ly = logf(fmaxf(lk, 1e-30f));
                Sw += 1.0f;
                Sx += lg;
                Sy += ly;
                Sxx += lg * lg;
                Sxy += lg * ly;
            }
        }
        const float denom = Sw * Sxx - Sx * Sx;
        const float slope =
            (fabsf(denom) > 1e-12f) ? (Sw * Sxy - Sx * Sy) / denom : 0.0f;
        float fd = (Sw > 1.0f) ? -slope : 0.0f;

        const int s = (base + tid) & (SEQ - 1);  // time mask: s < MAX_K -> 0
        if (s < MAXK) fd = 0.0f;
        sm_fd[tid] = fd;
    }
    __syncthreads();

    // Phase 2: hoist fd values, then pure store burst.
    const int h4 = tid & (H4 - 1);          // loop-invariant column block
    const int rbase = tid >> 7;             // 0 or 1
    const v4f Wv = W4[h4];
    const v4f bv = b4[h4];

    float hreg[PPB / 2];
#pragma unroll
    for (int i = 0; i < PPB / 2; ++i) hreg[i] = sm_fd[i * 2 + rbase];

    v4f* outb = out + (size_t)base * H4 + (size_t)rbase * H4 + h4;
#pragma unroll
    for (int i = 0; i < PPB / 2; ++i) {
        const float h = hreg[i];
        v4f o;
        o.x = fmaxf(fmaf(h, Wv.x, bv.x), 0.0f);
        o.y = fmaxf(fmaf(h, Wv.y, bv.y), 0.0f);
        o.z = fmaxf(fmaf(h, Wv.z, bv.z), 0.0f);
        o.w = fmaxf(fmaf(h, Wv.w, bv.w), 0.0f);
        outb[(size_t)i * 2 * H4] = o;
    }
}

extern "C" void kernel_launch(void* const* d_in, const int* in_sizes, int n_in,
                              void* d_out, int out_size, void* d_ws,
                              size_t ws_size, hipStream_t stream) {
    const float* x = (const float*)d_in[0];   // (16, 4096, 8)
    const v4f* W4 = (const v4f*)d_in[1];      // (512,1) contiguous
    const v4f* b4 = (const v4f*)d_in[2];      // (512,)
    v4f* out = (v4f*)d_out;                   // (16, 4096, 512) fp32

    const int P = in_sizes[0] / 8;            // 65536 positions
    fused_kernel<<<P / PPB, BLK, 0, stream>>>(x, W4, b4, out, P);
}